// Round 2
// baseline (270.711 us; speedup 1.0000x reference)
//
#include <hip/hip_runtime.h>
#include <math.h>

#define N_NODES 100000
#define N_EDGES 1600000
#define EPS_    1e-5f
#define PAD     64          // ELL row capacity; P(Poisson(16) > 64) ~ 1e-20

#define NB_BUILD 6250       // E/256 exactly: one edge per thread (6250*256 == 1.6M)
#define LIN_CHUNKS 1563     // ceil(N_NODES/64): 64 nodes per lin wave, lane = node

// R10: Phase B was LDS-throughput-bound (R8 vs R9: traffic changed 133->158MB,
// dur identical 125us; 100K nodes * 128 wave-LDS-ops * 5.8cy / 256 CU ~= 121us).
// New Phase B: lane = node, acc[64] in VGPRs, weights via wave-uniform scalar
// loads (s_load broadcast). Zero LDS, zero shuffles, no __syncthreads.
// hb_h eliminated: gather recomputes h from x (3 FMAs) instead of a 128B read.

// ---- bf16 helpers (raw ushort storage, RNE on pack) -----------------------
__device__ __forceinline__ float bf2f(unsigned short u) {
    union { unsigned int i; float f; } v; v.i = (unsigned int)u << 16; return v.f;
}
__device__ __forceinline__ unsigned short f2bf(float f) {
    union { float f; unsigned int i; } v; v.f = f;
    unsigned int b = v.i + 0x7FFFu + ((v.i >> 16) & 1u);   // round-to-nearest-even
    return (unsigned short)(b >> 16);
}

// ---------------------------------------------------------------------------
// Kernel 1: merged ELL build + lin.
// Phase A: one edge per thread: atomicAdd(cnt[dst]) + scattered ell store.
// Phase B (waves 0..1562 only): lane = node; for k in 0..63:
//   h_k = relu(x . W1[:,k] + b1[k])   (uniform scalar weight broadcasts)
//   acc[c] += h_k * Wg[k][c]          (64 independent VGPR chains, full ILP)
// hb_g stored UNSCALED (cnt not final); ell store issued after Phase B so the
// atomic return drains in Phase B's shadow for the lin waves.
// ---------------------------------------------------------------------------
__global__ void build_lin_kernel(const int* __restrict__ src,
                                 const int* __restrict__ dst,
                                 const float* __restrict__ x,
                                 const float* __restrict__ W1,
                                 const float* __restrict__ b1,
                                 const float* __restrict__ Wg,
                                 int* __restrict__ cnt,
                                 int* __restrict__ ell,
                                 unsigned short* __restrict__ hb_g)
{
    const int tl   = threadIdx.x;
    const int gtid = blockIdx.x * 256 + tl;      // grid covers E exactly

    // ---- Phase A: issue edge atomic (return consumed after Phase B) ------
    const int d   = dst[gtid];
    const int s   = src[gtid];
    const int pos = atomicAdd(&cnt[d], 1);

    // ---- Phase B: lin chunk, lane = node ---------------------------------
    const int chunk = blockIdx.x * 4 + (tl >> 6);
    if (chunk < LIN_CHUNKS) {
        const int lane = tl & 63;
        const int n    = chunk * 64 + lane;
        const bool act = (n < N_NODES);
        float x0 = 0.f, x1 = 0.f, x2 = 0.f;
        if (act) { x0 = x[n * 3]; x1 = x[n * 3 + 1]; x2 = x[n * 3 + 2]; }

        float acc[64];
#pragma unroll
        for (int c = 0; c < 64; ++c) acc[c] = 0.f;

#pragma unroll 2
        for (int k = 0; k < 64; ++k) {
            const float w0 = W1[k];              // wave-uniform -> s_load
            const float w1 = W1[64 + k];
            const float w2 = W1[128 + k];
            const float bb = b1[k];
            float hk = fmaf(x0, w0, fmaf(x1, w1, fmaf(x2, w2, bb)));
            hk = fmaxf(hk, 0.f);
            const float* __restrict__ wr = Wg + k * 64;   // uniform row
#pragma unroll
            for (int c = 0; c < 64; ++c) acc[c] = fmaf(hk, wr[c], acc[c]);
        }

        if (act) {
            unsigned int o[32];
#pragma unroll
            for (int c = 0; c < 32; ++c)
                o[c] = (unsigned int)f2bf(acc[2 * c])
                     | ((unsigned int)f2bf(acc[2 * c + 1]) << 16);
            uint4* __restrict__ dp = (uint4*)(hb_g + (size_t)n * 64);
#pragma unroll
            for (int q = 0; q < 8; ++q)
                dp[q] = make_uint4(o[4 * q], o[4 * q + 1], o[4 * q + 2], o[4 * q + 3]);
        }
    }

    // ---- Phase A completion: scattered ell store -------------------------
    if (pos < PAD) ell[d * PAD + pos] = s;
}

// ---------------------------------------------------------------------------
// Kernel 2: hb_g[n][c] *= rsqrt(cnt[n]+1)  (in place, dword grain, ~6 us)
// ---------------------------------------------------------------------------
__global__ void scale_kernel(const int* __restrict__ cnt,
                             unsigned int* __restrict__ g2)
{
    const int t = blockIdx.x * blockDim.x + threadIdx.x;
    if (t >= N_NODES * 32) return;
    const int node = t >> 5;
    const float di = rsqrtf((float)(cnt[node] + 1));
    const unsigned int v = g2[t];
    const float lo = bf2f((unsigned short)(v & 0xFFFFu)) * di;
    const float hi = bf2f((unsigned short)(v >> 16)) * di;
    g2[t] = (unsigned int)f2bf(lo) | ((unsigned int)f2bf(hi) << 16);
}

// ---------------------------------------------------------------------------
// Kernel 3: gather + epilogue. One wave per dst node, lane = channel.
//   h   = relu(x[n] . W1[:,lane] + b1[lane])   (recomputed; hb_h removed)
//   acc = hgs[n] (self) + sum over ELL row hgs[src]   (dinv[src] pre-folded)
//   h2  = relu(dinv[n]*acc + bg);  out = LayerNorm128([h,h2])*gamma + beta
// ---------------------------------------------------------------------------
__global__ void gather_final_kernel(const unsigned short* __restrict__ hb_g,
                                    const int* __restrict__ cnt,
                                    const int* __restrict__ ell,
                                    const float* __restrict__ x,
                                    const float* __restrict__ W1,
                                    const float* __restrict__ b1,
                                    const float* __restrict__ bg,
                                    const float* __restrict__ gamma,
                                    const float* __restrict__ beta,
                                    float* __restrict__ out)
{
    const int lane = threadIdx.x & 63;
    const int n    = blockIdx.x * (blockDim.x >> 6) + (threadIdx.x >> 6);
    if (n >= N_NODES) return;

    // recompute h (issue loads early; x* are wave-uniform -> scalar loads)
    const float xx0 = x[n * 3], xx1 = x[n * 3 + 1], xx2 = x[n * 3 + 2];
    const float w0 = W1[lane], w1 = W1[64 + lane], w2 = W1[128 + lane];
    const float bb = b1[lane];

    const int c    = cnt[n];
    const float di = rsqrtf((float)(c + 1));
    const int deg  = (c < PAD) ? c : PAD;
    const int* __restrict__ row = ell + n * PAD;

    float acc = bf2f(hb_g[n * 64 + lane]);           // self loop (scaled)

    int j = 0;
    for (; j + 8 <= deg; j += 8) {                   // 8 gathers in flight
        const int4 r0 = *(const int4*)(row + j);
        const int4 r1 = *(const int4*)(row + j + 4);
        const float a0 = bf2f(hb_g[r0.x * 64 + lane]);
        const float a1 = bf2f(hb_g[r0.y * 64 + lane]);
        const float a2 = bf2f(hb_g[r0.z * 64 + lane]);
        const float a3 = bf2f(hb_g[r0.w * 64 + lane]);
        const float a4 = bf2f(hb_g[r1.x * 64 + lane]);
        const float a5 = bf2f(hb_g[r1.y * 64 + lane]);
        const float a6 = bf2f(hb_g[r1.z * 64 + lane]);
        const float a7 = bf2f(hb_g[r1.w * 64 + lane]);
        acc += ((a0 + a1) + (a2 + a3)) + ((a4 + a5) + (a6 + a7));
    }
    if (j + 4 <= deg) {
        const int4 r0 = *(const int4*)(row + j);
        acc += (bf2f(hb_g[r0.x * 64 + lane]) + bf2f(hb_g[r0.y * 64 + lane]))
             + (bf2f(hb_g[r0.z * 64 + lane]) + bf2f(hb_g[r0.w * 64 + lane]));
        j += 4;
    }
    for (; j < deg; ++j) acc += bf2f(hb_g[row[j] * 64 + lane]);

    float h = fmaf(xx0, w0, fmaf(xx1, w1, fmaf(xx2, w2, bb)));
    h = fmaxf(h, 0.f);

    float h2 = fmaxf(fmaf(di, acc, bg[lane]), 0.0f);

    float sum = h + h2;
#pragma unroll
    for (int o = 32; o > 0; o >>= 1) sum += __shfl_xor(sum, o, 64);
    const float mu = sum * (1.0f / 128.0f);

    const float d0 = h - mu;
    const float d1 = h2 - mu;
    float vs = d0 * d0 + d1 * d1;
#pragma unroll
    for (int o = 32; o > 0; o >>= 1) vs += __shfl_xor(vs, o, 64);
    const float r = rsqrtf(vs * (1.0f / 128.0f) + EPS_);

    out[n * 128 + lane]      = d0 * r * gamma[lane]      + beta[lane];
    out[n * 128 + 64 + lane] = d1 * r * gamma[64 + lane] + beta[64 + lane];
}

// ---------------------------------------------------------------------------
extern "C" void kernel_launch(void* const* d_in, const int* in_sizes, int n_in,
                              void* d_out, int out_size, void* d_ws, size_t ws_size,
                              hipStream_t stream)
{
    const float* x     = (const float*)d_in[0];
    const int*   edge  = (const int*)  d_in[1];   // [2, E]: row0 = src, row1 = dst
    const float* W1    = (const float*)d_in[2];
    const float* b1    = (const float*)d_in[3];
    const float* Wg    = (const float*)d_in[4];
    const float* bg    = (const float*)d_in[5];
    const float* gamma = (const float*)d_in[6];
    const float* beta  = (const float*)d_in[7];
    float*       out   = (float*)d_out;

    // Workspace layout (~38.8 MB): hb_g | ell | cnt  (16B-aligned)
    char*  ws  = (char*)d_ws;
    size_t p   = 0;
    unsigned short* hb_g = (unsigned short*)(ws + p); p += (size_t)N_NODES * 64 * sizeof(unsigned short);
    int*            ell  = (int*)           (ws + p); p += (size_t)N_NODES * PAD * sizeof(int);
    int*            cnt  = (int*)           (ws + p);

    const int* src = edge;
    const int* dst = edge + N_EDGES;

    hipMemsetAsync(cnt, 0, (size_t)N_NODES * sizeof(int), stream);

    build_lin_kernel<<<NB_BUILD, 256, 0, stream>>>(src, dst, x, W1, b1, Wg,
                                                   cnt, ell, hb_g);
    scale_kernel<<<(N_NODES * 32 + 255) / 256, 256, 0, stream>>>(cnt, (unsigned int*)hb_g);
    gather_final_kernel<<<(N_NODES + 3) / 4, 256, 0, stream>>>(hb_g, cnt, ell,
                                                               x, W1, b1,
                                                               bg, gamma, beta, out);
}

// Round 3
// 267.562 us; speedup vs baseline: 1.0118x; 1.0118x over previous
//
#include <hip/hip_runtime.h>
#include <math.h>

#define N_NODES 100000
#define N_EDGES 1600000
#define EPS_    1e-5f
#define PAD     64          // ELL row capacity; P(Poisson(16) > 64) ~ 1e-20

#define NB_BUILD 6250       // E/256 exactly: one edge per thread (6250*256 == 1.6M)
#define LIN_CHUNKS 1563     // ceil(N_NODES/64): 64 nodes per lin wave, lane = node

// R11: build was L2-ATOMIC-LINE-LOCK bound. Evidence: R8/R9/R10 changed traffic
// (133/158/120 MB), VALU (17/17/5%), LDS (16KB/16KB/0) -- duration pinned at
// 125-129us. Only invariant: 1.6M atomicAdd to cnt[] with 16 counters/64B line
// -> ~256 serialized line-locked ops per line ~= 305K cy ~= 127us. Fix: stride
// counters 1 per 128B line (CNT_STRIDE=32 ints). Same atomic count; same-line
// serialization 256 -> 16 (same-address only), pipelined across 100K lines.
#define CNT_STRIDE 32       // one counter per 128B line

// ---- bf16 helpers (raw ushort storage, RNE on pack) -----------------------
__device__ __forceinline__ float bf2f(unsigned short u) {
    union { unsigned int i; float f; } v; v.i = (unsigned int)u << 16; return v.f;
}
__device__ __forceinline__ unsigned short f2bf(float f) {
    union { float f; unsigned int i; } v; v.f = f;
    unsigned int b = v.i + 0x7FFFu + ((v.i >> 16) & 1u);   // round-to-nearest-even
    return (unsigned short)(b >> 16);
}

// ---------------------------------------------------------------------------
// Kernel 1: merged ELL build + lin.
// Phase A: one edge per thread: atomicAdd(cnt[dst*32]) + scattered ell store.
// Phase B (waves 0..1562 only): lane = node; weights via wave-uniform scalar
// broadcasts; acc[64] in VGPRs. hb_g stored UNSCALED (cnt not final).
// ---------------------------------------------------------------------------
__global__ void build_lin_kernel(const int* __restrict__ src,
                                 const int* __restrict__ dst,
                                 const float* __restrict__ x,
                                 const float* __restrict__ W1,
                                 const float* __restrict__ b1,
                                 const float* __restrict__ Wg,
                                 int* __restrict__ cnt,
                                 int* __restrict__ ell,
                                 unsigned short* __restrict__ hb_g)
{
    const int tl   = threadIdx.x;
    const int gtid = blockIdx.x * 256 + tl;      // grid covers E exactly

    // ---- Phase A: issue edge atomic (return consumed after Phase B) ------
    const int d   = dst[gtid];
    const int s   = src[gtid];
    const int pos = atomicAdd(&cnt[(size_t)d * CNT_STRIDE], 1);

    // ---- Phase B: lin chunk, lane = node ---------------------------------
    const int chunk = blockIdx.x * 4 + (tl >> 6);
    if (chunk < LIN_CHUNKS) {
        const int lane = tl & 63;
        const int n    = chunk * 64 + lane;
        const bool act = (n < N_NODES);
        float x0 = 0.f, x1 = 0.f, x2 = 0.f;
        if (act) { x0 = x[n * 3]; x1 = x[n * 3 + 1]; x2 = x[n * 3 + 2]; }

        float acc[64];
#pragma unroll
        for (int c = 0; c < 64; ++c) acc[c] = 0.f;

#pragma unroll 2
        for (int k = 0; k < 64; ++k) {
            const float w0 = W1[k];              // wave-uniform -> s_load
            const float w1 = W1[64 + k];
            const float w2 = W1[128 + k];
            const float bb = b1[k];
            float hk = fmaf(x0, w0, fmaf(x1, w1, fmaf(x2, w2, bb)));
            hk = fmaxf(hk, 0.f);
            const float* __restrict__ wr = Wg + k * 64;   // uniform row
#pragma unroll
            for (int c = 0; c < 64; ++c) acc[c] = fmaf(hk, wr[c], acc[c]);
        }

        if (act) {
            unsigned int o[32];
#pragma unroll
            for (int c = 0; c < 32; ++c)
                o[c] = (unsigned int)f2bf(acc[2 * c])
                     | ((unsigned int)f2bf(acc[2 * c + 1]) << 16);
            uint4* __restrict__ dp = (uint4*)(hb_g + (size_t)n * 64);
#pragma unroll
            for (int q = 0; q < 8; ++q)
                dp[q] = make_uint4(o[4 * q], o[4 * q + 1], o[4 * q + 2], o[4 * q + 3]);
        }
    }

    // ---- Phase A completion: scattered ell store -------------------------
    if (pos < PAD) ell[d * PAD + pos] = s;
}

// ---------------------------------------------------------------------------
// Kernel 2: hb_g[n][c] *= rsqrt(cnt[n]+1)  (in place, dword grain, ~6 us)
// ---------------------------------------------------------------------------
__global__ void scale_kernel(const int* __restrict__ cnt,
                             unsigned int* __restrict__ g2)
{
    const int t = blockIdx.x * blockDim.x + threadIdx.x;
    if (t >= N_NODES * 32) return;
    const int node = t >> 5;
    const float di = rsqrtf((float)(cnt[(size_t)node * CNT_STRIDE] + 1));
    const unsigned int v = g2[t];
    const float lo = bf2f((unsigned short)(v & 0xFFFFu)) * di;
    const float hi = bf2f((unsigned short)(v >> 16)) * di;
    g2[t] = (unsigned int)f2bf(lo) | ((unsigned int)f2bf(hi) << 16);
}

// ---------------------------------------------------------------------------
// Kernel 3: gather + epilogue. One wave per dst node, lane = channel.
//   h   = relu(x[n] . W1[:,lane] + b1[lane])   (recomputed; no hb_h)
//   acc = hgs[n] (self) + sum over ELL row hgs[src]   (dinv[src] pre-folded)
//   h2  = relu(dinv[n]*acc + bg);  out = LayerNorm128([h,h2])*gamma + beta
// ---------------------------------------------------------------------------
__global__ void gather_final_kernel(const unsigned short* __restrict__ hb_g,
                                    const int* __restrict__ cnt,
                                    const int* __restrict__ ell,
                                    const float* __restrict__ x,
                                    const float* __restrict__ W1,
                                    const float* __restrict__ b1,
                                    const float* __restrict__ bg,
                                    const float* __restrict__ gamma,
                                    const float* __restrict__ beta,
                                    float* __restrict__ out)
{
    const int lane = threadIdx.x & 63;
    const int n    = blockIdx.x * (blockDim.x >> 6) + (threadIdx.x >> 6);
    if (n >= N_NODES) return;

    // recompute h (issue loads early; x* are wave-uniform -> scalar loads)
    const float xx0 = x[n * 3], xx1 = x[n * 3 + 1], xx2 = x[n * 3 + 2];
    const float w0 = W1[lane], w1 = W1[64 + lane], w2 = W1[128 + lane];
    const float bb = b1[lane];

    const int c    = cnt[(size_t)n * CNT_STRIDE];
    const float di = rsqrtf((float)(c + 1));
    const int deg  = (c < PAD) ? c : PAD;
    const int* __restrict__ row = ell + n * PAD;

    float acc = bf2f(hb_g[n * 64 + lane]);           // self loop (scaled)

    int j = 0;
    for (; j + 8 <= deg; j += 8) {                   // 8 gathers in flight
        const int4 r0 = *(const int4*)(row + j);
        const int4 r1 = *(const int4*)(row + j + 4);
        const float a0 = bf2f(hb_g[r0.x * 64 + lane]);
        const float a1 = bf2f(hb_g[r0.y * 64 + lane]);
        const float a2 = bf2f(hb_g[r0.z * 64 + lane]);
        const float a3 = bf2f(hb_g[r0.w * 64 + lane]);
        const float a4 = bf2f(hb_g[r1.x * 64 + lane]);
        const float a5 = bf2f(hb_g[r1.y * 64 + lane]);
        const float a6 = bf2f(hb_g[r1.z * 64 + lane]);
        const float a7 = bf2f(hb_g[r1.w * 64 + lane]);
        acc += ((a0 + a1) + (a2 + a3)) + ((a4 + a5) + (a6 + a7));
    }
    if (j + 4 <= deg) {
        const int4 r0 = *(const int4*)(row + j);
        acc += (bf2f(hb_g[r0.x * 64 + lane]) + bf2f(hb_g[r0.y * 64 + lane]))
             + (bf2f(hb_g[r0.z * 64 + lane]) + bf2f(hb_g[r0.w * 64 + lane]));
        j += 4;
    }
    for (; j < deg; ++j) acc += bf2f(hb_g[row[j] * 64 + lane]);

    float h = fmaf(xx0, w0, fmaf(xx1, w1, fmaf(xx2, w2, bb)));
    h = fmaxf(h, 0.f);

    float h2 = fmaxf(fmaf(di, acc, bg[lane]), 0.0f);

    float sum = h + h2;
#pragma unroll
    for (int o = 32; o > 0; o >>= 1) sum += __shfl_xor(sum, o, 64);
    const float mu = sum * (1.0f / 128.0f);

    const float d0 = h - mu;
    const float d1 = h2 - mu;
    float vs = d0 * d0 + d1 * d1;
#pragma unroll
    for (int o = 32; o > 0; o >>= 1) vs += __shfl_xor(vs, o, 64);
    const float r = rsqrtf(vs * (1.0f / 128.0f) + EPS_);

    out[n * 128 + lane]      = d0 * r * gamma[lane]      + beta[lane];
    out[n * 128 + 64 + lane] = d1 * r * gamma[64 + lane] + beta[64 + lane];
}

// ---------------------------------------------------------------------------
extern "C" void kernel_launch(void* const* d_in, const int* in_sizes, int n_in,
                              void* d_out, int out_size, void* d_ws, size_t ws_size,
                              hipStream_t stream)
{
    const float* x     = (const float*)d_in[0];
    const int*   edge  = (const int*)  d_in[1];   // [2, E]: row0 = src, row1 = dst
    const float* W1    = (const float*)d_in[2];
    const float* b1    = (const float*)d_in[3];
    const float* Wg    = (const float*)d_in[4];
    const float* bg    = (const float*)d_in[5];
    const float* gamma = (const float*)d_in[6];
    const float* beta  = (const float*)d_in[7];
    float*       out   = (float*)d_out;

    // Workspace layout (~51.2 MB): hb_g | ell | cnt(strided)  (16B-aligned)
    char*  ws  = (char*)d_ws;
    size_t p   = 0;
    unsigned short* hb_g = (unsigned short*)(ws + p); p += (size_t)N_NODES * 64 * sizeof(unsigned short);
    int*            ell  = (int*)           (ws + p); p += (size_t)N_NODES * PAD * sizeof(int);
    int*            cnt  = (int*)           (ws + p);

    const int* src = edge;
    const int* dst = edge + N_EDGES;

    hipMemsetAsync(cnt, 0, (size_t)N_NODES * CNT_STRIDE * sizeof(int), stream);

    build_lin_kernel<<<NB_BUILD, 256, 0, stream>>>(src, dst, x, W1, b1, Wg,
                                                   cnt, ell, hb_g);
    scale_kernel<<<(N_NODES * 32 + 255) / 256, 256, 0, stream>>>(cnt, (unsigned int*)hb_g);
    gather_final_kernel<<<(N_NODES + 3) / 4, 256, 0, stream>>>(hb_g, cnt, ell,
                                                               x, W1, b1,
                                                               bg, gamma, beta, out);
}